// Round 11
// baseline (242.813 us; speedup 1.0000x reference)
//
#include <hip/hip_runtime.h>
#include <stdint.h>
#include <math.h>

// ---------- types ----------
typedef short s16x8 __attribute__((ext_vector_type(8)));   // 8 bf16 (4 VGPR)
typedef float f32x4 __attribute__((ext_vector_type(4)));
typedef float f32x16 __attribute__((ext_vector_type(16)));

__device__ __forceinline__ unsigned short f2bf(float f) {
    union { float f; uint32_t u; } x; x.f = f;
    uint32_t r = x.u + 0x7FFFu + ((x.u >> 16) & 1u);   // RNE
    return (unsigned short)(r >> 16);
}

__device__ __forceinline__ uint32_t cvtpk_bf16(float lo, float hi) {
    uint32_t r;
    asm("v_cvt_pk_bf16_f32 %0, %1, %2" : "=v"(r) : "v"(lo), "v"(hi));
    return r;
}

#define GLD_LDS16(gp, lp) __builtin_amdgcn_global_load_lds( \
    (const __attribute__((address_space(1))) uint32_t*)(gp), \
    (__attribute__((address_space(3))) uint32_t*)(lp), 16, 0, 0)

#define MFMA16x16x32(a, b, c) __builtin_amdgcn_mfma_f32_16x16x32_bf16((a), (b), (c), 0, 0, 0)
#define MFMA32x32x16(a, b, c) __builtin_amdgcn_mfma_f32_32x32x16_bf16((a), (b), (c), 0, 0, 0)

// lane-half exchange
__device__ __forceinline__ void plswap(uint32_t a, uint32_t b, int lh, uint32_t& x, uint32_t& y) {
#if __has_builtin(__builtin_amdgcn_permlane32_swap)
    auto r = __builtin_amdgcn_permlane32_swap(a, b, false, false);
    x = (uint32_t)r[0]; y = (uint32_t)r[1];
#else
    uint32_t as = (uint32_t)__shfl_xor((int)a, 32, 64);
    uint32_t bs = (uint32_t)__shfl_xor((int)b, 32, 64);
    x = lh ? bs : a;
    y = lh ? b : as;
#endif
}

// ---------- merged convert kernel ----------
__global__ void cvt_all_kernel(const float* __restrict__ x,
                               const float* __restrict__ Wq, const float* __restrict__ Wk,
                               const float* __restrict__ Wv, const float* __restrict__ Wp,
                               unsigned short* __restrict__ xb,
                               unsigned short* __restrict__ WtQKV, unsigned short* __restrict__ WtP,
                               int xunits) {
    int u = blockIdx.x * blockDim.x + threadIdx.x;
    if (u < xunits) {
        int i = u * 4;
        float4 v = *(const float4*)(x + i);
        unsigned short o0 = f2bf(v.x), o1 = f2bf(v.y), o2 = f2bf(v.z), o3 = f2bf(v.w);
        uint64_t packed = (uint64_t)o0 | ((uint64_t)o1 << 16) | ((uint64_t)o2 << 32) | ((uint64_t)o3 << 48);
        *(uint64_t*)(xb + i) = packed;
        return;
    }
    int id = (u - xunits) * 4;               // 0 .. 4*1048576-1
    int which = id >> 20, rem = id & 1048575;
    const float* src = (which == 0) ? Wq : (which == 1) ? Wk : (which == 2) ? Wv : Wp;
    float4 v = *(const float4*)(src + rem);
    unsigned short* dst;
    if (which < 3) {
        int h = rem >> 16, c = (rem >> 6) & 1023, d = rem & 63;
        dst = WtQKV + (size_t)(which * 1024 + h * 64 + d) * 1024 + c;
    } else {
        int c = rem >> 10, n = rem & 1023;
        dst = WtP + (size_t)n * 1024 + c;
    }
    dst[0] = f2bf(v.x); dst[1024] = f2bf(v.y); dst[2048] = f2bf(v.z); dst[3072] = f2bf(v.w);
}

// ---------- unified deep-pipeline GEMM (T3+T4+T5), BM=128 BN=256 BK=32, 3-deep ----------
template<int MODE, int CPX>
__global__ __launch_bounds__(512, 4) void gemm_dp_kernel(
    const unsigned short* __restrict__ A, const unsigned short* __restrict__ Bt,
    void* __restrict__ Cout, unsigned short* __restrict__ vT,
    const float* __restrict__ bias)
{
    constexpr int K = 1024, NT = 32;     // K-tiles of 32
    __shared__ __align__(16) unsigned short LA[3][128 * 32];   // 8 KB each
    __shared__ __align__(16) unsigned short LB[3][256 * 32];   // 16 KB each

    const int t = threadIdx.x, w = t >> 6, l = t & 63, lr = l & 15, lg = l >> 4;
    const int wm2 = w >> 2, wn4 = w & 3;

    int bid = blockIdx.x;
    int swz = (bid & 7) * CPX + (bid >> 3);
    const int bm = (swz & 63) << 7, bn = (swz >> 6) << 8;

    const unsigned short* Ab = A + (size_t)bm * K;
    const unsigned short* Bb = Bt + (size_t)bn * K;

    int sArow, sAce, sBrow[2], sBce[2];
    {
        int u = t >> 4, x = (t & 15) ^ (u & 15);
        sArow = 4 * u + (x >> 2); sAce = (x & 3) << 3;
        #pragma unroll
        for (int i2 = 0; i2 < 2; ++i2) {
            int i = t + i2 * 512;
            int ub = i >> 4, xb2 = (i & 15) ^ (ub & 15);
            sBrow[i2] = 4 * ub + (xb2 >> 2); sBce[i2] = (xb2 & 3) << 3;
        }
    }

    int aoff[4], boff[4];
    #pragma unroll
    for (int m = 0; m < 4; ++m) {
        int u = 16 * wm2 + 4 * m + (lr >> 2);
        aoff[m] = u * 256 + (((lg + 4 * (lr & 3)) ^ (u & 15)) << 4);
    }
    #pragma unroll
    for (int n = 0; n < 4; ++n) {
        int u = 16 * wn4 + 4 * n + (lr >> 2);
        boff[n] = u * 256 + (((lg + 4 * (lr & 3)) ^ (u & 15)) << 4);
    }

    f32x4 acc[4][4] = {};

    GLD_LDS16(Ab + (size_t)sArow * K + 0 + sAce, &LA[0][t * 8]);
    #pragma unroll
    for (int i2 = 0; i2 < 2; ++i2)
        GLD_LDS16(Bb + (size_t)sBrow[i2] * K + 0 + sBce[i2], &LB[0][(t + i2 * 512) * 8]);
    GLD_LDS16(Ab + (size_t)sArow * K + 32 + sAce, &LA[1][t * 8]);
    #pragma unroll
    for (int i2 = 0; i2 < 2; ++i2)
        GLD_LDS16(Bb + (size_t)sBrow[i2] * K + 32 + sBce[i2], &LB[1][(t + i2 * 512) * 8]);
    asm volatile("s_waitcnt vmcnt(3)" ::: "memory");
    __builtin_amdgcn_sched_barrier(0);
    __builtin_amdgcn_s_barrier();

    int cur = 0;
    for (int j = 0; j < NT; ++j) {
        const int dst = (cur >= 1) ? cur - 1 : cur + 2;      // (j+2) % 3
        const bool st = (j + 2 < NT);
        const int k2 = (j + 2) << 5;
        s16x8 af[4], bfr[4];
        #pragma unroll
        for (int m = 0; m < 4; ++m)
            af[m] = *(const s16x8*)((const char*)LA[cur] + aoff[m]);
        #pragma unroll
        for (int n = 0; n < 4; ++n)
            bfr[n] = *(const s16x8*)((const char*)LB[cur] + boff[n]);
        if (st) {
            GLD_LDS16(Ab + (size_t)sArow * K + k2 + sAce, &LA[dst][t * 8]);
            #pragma unroll
            for (int i2 = 0; i2 < 2; ++i2)
                GLD_LDS16(Bb + (size_t)sBrow[i2] * K + k2 + sBce[i2], &LB[dst][(t + i2 * 512) * 8]);
        }
        __builtin_amdgcn_s_barrier();
        asm volatile("s_waitcnt lgkmcnt(0)" ::: "memory");
        __builtin_amdgcn_sched_barrier(0);
        __builtin_amdgcn_s_setprio(1);
        #pragma unroll
        for (int m = 0; m < 4; ++m)
            #pragma unroll
            for (int n = 0; n < 4; ++n)
                acc[m][n] = MFMA16x16x32(af[m], bfr[n], acc[m][n]);
        __builtin_amdgcn_s_setprio(0);
        if (j + 1 < NT) {
            if (st) { asm volatile("s_waitcnt vmcnt(3)" ::: "memory"); }
            else    { asm volatile("s_waitcnt vmcnt(0)" ::: "memory"); }
            __builtin_amdgcn_sched_barrier(0);
        }
        __builtin_amdgcn_s_barrier();
        cur = (cur == 2) ? 0 : cur + 1;
    }

    if (MODE == 1) {
        float* C = (float*)Cout;
        #pragma unroll
        for (int mi = 0; mi < 4; ++mi)
            #pragma unroll
            for (int ni = 0; ni < 4; ++ni) {
                int col = bn + wn4 * 64 + ni * 16 + lr;
                float bv = bias[col];
                int row0 = bm + wm2 * 64 + mi * 16 + lg * 4;
                #pragma unroll
                for (int r = 0; r < 4; ++r)
                    C[(size_t)(row0 + r) * 1024 + col] = acc[mi][ni][r] + bv;
            }
    } else {
        unsigned short* qkv2 = (unsigned short*)Cout;
        const bool isV = (bn >= 2048);
        const float sc = (bn < 1024) ? (0.03125f * 1.44269504088896341f) : 1.0f;
        #pragma unroll
        for (int mi = 0; mi < 4; ++mi)
            #pragma unroll
            for (int ni = 0; ni < 4; ++ni) {
                int col = bn + wn4 * 64 + ni * 16 + lr;
                int row0 = bm + wm2 * 64 + mi * 16 + lg * 4;
                if (!isV) {
                    #pragma unroll
                    for (int r = 0; r < 4; ++r)
                        qkv2[(size_t)(row0 + r) * 2048 + col] = f2bf(acc[mi][ni][r] * sc);
                } else {
                    int h = (col >> 6) & 15, d = col & 63;
                    size_t vb = ((size_t)((row0 >> 11) * 16 + h) * 64 + d) * 2048 + (row0 & 2047);
                    uint32_t u0 = (uint32_t)f2bf(acc[mi][ni][0]) | ((uint32_t)f2bf(acc[mi][ni][1]) << 16);
                    uint32_t u1 = (uint32_t)f2bf(acc[mi][ni][2]) | ((uint32_t)f2bf(acc[mi][ni][3]) << 16);
                    *(uint32_t*)&vT[vb]     = u0;
                    *(uint32_t*)&vT[vb + 2] = u1;
                }
            }
    }
}

// ---------- flash attention: KV-parity split, 32x32 MFMA, in-register P,
// MFMA ones-row-sum for l (R7 trick: only l_acc[0] is rescaled/read) ----------
// Wave (ws, wp): slice ws owns 32 q-rows; parity wp processes s in [32wp, 32wp+32)
// of each 64-kv LDS tile. Private (m, l_acc, o) per wave; LDS combine at block end.
// S^T = mfma(K, Q): col q = lane&31, s_loc = (r&3)+8*(r>>2)+4*lh (within half).
// LDS tiles 64 rows x 128 B: super-row u = row>>1 (256 B, 16 slots of 16 B);
// slot = (chunk + 8*(row&1)) ^ (u & 15).
__device__ __forceinline__ void proc32h(
    const unsigned short* __restrict__ Ksb, const unsigned short* __restrict__ Vtb,
    const s16x8* qf, f32x16* o, float& m_r, f32x16& l_acc, s16x8 onesf,
    int qms, bool domask, int lq, int lh, int wp)
{
    const int ub = lq >> 1;
    const int vb8 = (lq & 1) << 3;
    f32x16 S = {};
    __builtin_amdgcn_s_setprio(1);
    #pragma unroll
    for (int kd = 0; kd < 4; ++kd) {
        s16x8 kf = *(const s16x8*)((const char*)Ksb + (wp * 16 + ub) * 256
                                   + ((((2 * kd + lh) + vb8) ^ ub) << 4));
        S = MFMA32x32x16(kf, qf[kd], S);
    }
    __builtin_amdgcn_s_setprio(0);
    if (domask) {
        #pragma unroll
        for (int r = 0; r < 16; ++r) {
            int s_loc = (r & 3) + 8 * (r >> 2) + 4 * lh;
            S[r] = (s_loc <= qms) ? S[r] : -1e30f;
        }
    }
    // row max over this half: tree over 16 regs + 1 shuffle (lane^32 = other s_loc set)
    float zm = fmaxf(S[0], S[1]);
    #pragma unroll
    for (int r = 2; r < 16; r += 2) zm = fmaxf(fmaxf(zm, S[r]), S[r + 1]);
    zm = fmaxf(zm, __shfl_xor(zm, 32, 64));
    const bool defer = (__all(zm <= m_r + 8.0f) != 0);   // T13
    if (!defer) {
        float mn = fmaxf(m_r, zm);
        float alpha = exp2f(m_r - mn);
        m_r = mn;
        l_acc[0] *= alpha;
        o[0] *= alpha;
        o[1] *= alpha;
    }
    uint32_t pk[8];
    #pragma unroll
    for (int r = 0; r < 16; ++r)
        S[r] = exp2f(S[r] - m_r);
    #pragma unroll
    for (int hh = 0; hh < 8; ++hh)
        pk[hh] = cvtpk_bf16(S[2 * hh], S[2 * hh + 1]);
    // pf[jj]: B-frag P^T for k = s = 32*wp + 16*jj + 8*lh + j
    s16x8 pf[2];
    #pragma unroll
    for (int jj = 0; jj < 2; ++jj) {
        uint32_t w0, w1, w2, w3;
        plswap(pk[4 * jj + 0], pk[4 * jj + 2], lh, w0, w2);
        plswap(pk[4 * jj + 1], pk[4 * jj + 3], lh, w1, w3);
        union { uint32_t u[4]; s16x8 v; } pu;
        pu.u[0] = w0; pu.u[1] = w1; pu.u[2] = w2; pu.u[3] = w3;
        pf[jj] = pu.v;
    }
    __builtin_amdgcn_s_setprio(1);
    #pragma unroll
    for (int dblk = 0; dblk < 2; ++dblk)
        #pragma unroll
        for (int jj = 0; jj < 2; ++jj) {
            int kc = 2 * (2 * wp + jj) + lh;
            s16x8 vf = *(const s16x8*)((const char*)Vtb + (dblk * 16 + ub) * 256
                                       + (((kc + vb8) ^ ub) << 4));
            o[dblk] = MFMA32x32x16(vf, pf[jj], o[dblk]);
        }
    #pragma unroll
    for (int jj = 0; jj < 2; ++jj)
        l_acc = MFMA32x32x16(onesf, pf[jj], l_acc);   // row-sum on the matrix pipe
    __builtin_amdgcn_s_setprio(0);
}

// Block = 256 threads = 4 waves; one 64-row q-tile; waves: slice (w&1) x parity (w>>1).
// blockIdx decode: g = i&7 (XCD group = bh%8), j = i>>3; tq = 31-(j>>3) (LPT),
// bh = ((j&7)<<3)|g.
__global__ __launch_bounds__(256, 5) void attn_kernel(
    const unsigned short* __restrict__ qkv2, const unsigned short* __restrict__ vT,
    unsigned short* __restrict__ attnO, int T)
{
    __shared__ __align__(16) unsigned short SMEM[4][64 * 64];   // K0,K1,V0,V1; combine reuse

    const int i = blockIdx.x;
    const int g = i & 7, j = i >> 3;
    const int tq = 31 - (j >> 3);
    const int bh = ((j & 7) << 3) | g;
    const int b = bh >> 4, h = bh & 15;
    const int nkv = tq + 1;

    const int t = threadIdx.x, w = t >> 6, l = t & 63, lq = l & 31, lh = l >> 5;
    const int ws = w & 1, wp = w >> 1;
    const int c0 = tq * 64 + 32 * ws;

    const unsigned short* qbase = qkv2 + (size_t)b * T * 2048;
    const unsigned short* kbase = qbase + 1024 + h * 64;
    const unsigned short* vtb   = vT + (size_t)(b * 16 + h) * 64 * 2048;

    s16x8 qf[4];
    #pragma unroll
    for (int kd = 0; kd < 4; ++kd)
        qf[kd] = *(const s16x8*)(qbase + (size_t)(c0 + lq) * 2048 + h * 64 + kd * 16 + lh * 8);

    f32x16 o[2] = {}, l_acc = {};
    float m_r = -1e30f;
    s16x8 onesf;
    {
        union { uint32_t u[4]; s16x8 v; } ou;
        #pragma unroll
        for (int k2 = 0; k2 < 4; ++k2) ou.u[k2] = 0x3F803F80u;   // bf16 1.0 pairs
        onesf = ou.v;
    }

    // staging: 256 threads x 2 chunks per tile (512 chunks of 16 B each)
    int srow[2], sch[2];
    #pragma unroll
    for (int i2 = 0; i2 < 2; ++i2) {
        int c = t + i2 * 256;
        int su = c >> 4, sx = (c & 15) ^ (su & 15);
        srow[i2] = 2 * su + (sx >> 3); sch[i2] = (sx & 7) << 3;
    }
    auto STAGE = [&](int buf, int s0) {
        #pragma unroll
        for (int i2 = 0; i2 < 2; ++i2) {
            int c = t + i2 * 256;
            GLD_LDS16(kbase + (size_t)(s0 + srow[i2]) * 2048 + sch[i2], &SMEM[buf][c * 8]);
            GLD_LDS16(vtb + (size_t)srow[i2] * 2048 + s0 + sch[i2], &SMEM[2 + buf][c * 8]);
        }
    };

    STAGE(0, 0);
    __syncthreads();

    for (int kt = 0; kt < nkv; ++kt) {
        const int cur = kt & 1, nxt = cur ^ 1;
        if (kt + 1 < nkv) STAGE(nxt, (kt + 1) * 64);
        const int sbase = 64 * kt + 32 * wp;
        if (sbase <= c0 + 31)                                   // wave-uniform
            proc32h(SMEM[cur], SMEM[2 + cur], qf, o, m_r, l_acc, onesf,
                    c0 + lq - sbase, sbase + 31 > c0, lq, lh, wp);
        __syncthreads();
    }

    // ---- combine the two kv-parity halves (pairs w and w^2) through LDS ----
    float l_r = l_acc[0];
    float* fs = (float*)&SMEM[0][0];
    if (lh == 0) { fs[w * 64 + lq * 2] = m_r; fs[w * 64 + lq * 2 + 1] = l_r; }
    __syncthreads();
    float m_o = fs[(w ^ 2) * 64 + lq * 2], l_o = fs[(w ^ 2) * 64 + lq * 2 + 1];
    float M = fmaxf(m_r, m_o);
    float s_self = exp2f(m_r - M);
    float s_oth  = exp2f(m_o - M);
    float L = l_r * s_self + l_o * s_oth;
    float fsc = s_self / L;
    __syncthreads();                                            // ml region reused below
    float* cb = fs + ws * 2048;                                 // 8 KB per slice pair
    if (wp == 1) {
        #pragma unroll
        for (int dblk = 0; dblk < 2; ++dblk)
            #pragma unroll
            for (int r = 0; r < 16; ++r)
                cb[(dblk * 16 + r) * 64 + lq * 2 + lh] = o[dblk][r] * fsc;
    }
    __syncthreads();
    if (wp == 0) {
        #pragma unroll
        for (int dblk = 0; dblk < 2; ++dblk)
            #pragma unroll
            for (int r = 0; r < 16; r += 2) {
                float v0 = o[dblk][r] * fsc     + cb[(dblk * 16 + r) * 64 + lq * 2 + lh];
                float v1 = o[dblk][r + 1] * fsc + cb[(dblk * 16 + r + 1) * 64 + lq * 2 + lh];
                int d = dblk * 32 + (r & 3) + 8 * (r >> 2) + 4 * lh;
                uint32_t ua = cvtpk_bf16(v0, v1);
                *(uint32_t*)&attnO[(size_t)(b * T + c0 + lq) * 1024 + h * 64 + d] = ua;
            }
    }
}

// ---------- launch ----------
extern "C" void kernel_launch(void* const* d_in, const int* in_sizes, int n_in,
                              void* d_out, int out_size, void* d_ws, size_t ws_size,
                              hipStream_t stream) {
    const float* x  = (const float*)d_in[0];
    const float* Wq = (const float*)d_in[1];
    const float* Wk = (const float*)d_in[2];
    const float* Wv = (const float*)d_in[3];
    const float* Wp = (const float*)d_in[4];
    const float* bp = (const float*)d_in[5];
    float* out = (float*)d_out;

    const int T = 2048, C = 1024;
    const int BT = in_sizes[0] / C;      // 8192
    const int B  = BT / T;               // 4

    // workspace layout (bytes), total 92,274,688
    char* ws = (char*)d_ws;
    unsigned short* xb    = (unsigned short*)(ws);                        // 16,777,216
    unsigned short* WtQKV = (unsigned short*)(ws + 16777216);             //  6,291,456
    unsigned short* WtP   = (unsigned short*)(ws + 23068672);             //  2,097,152
    unsigned short* qkv2  = (unsigned short*)(ws + 25165824);             // 33,554,432 [8192][2048]
    unsigned short* vT    = (unsigned short*)(ws + 58720256);             // 16,777,216 [(b,h,d)][2048]
    unsigned short* attn  = (unsigned short*)(ws + 75497472);             // 16,777,216
    (void)ws_size; (void)n_in; (void)out_size;

    const int xunits = BT * C / 4;                       // 2,097,152
    const int wunits = 4 * 1024 * 1024 / 4;              // 1,048,576
    cvt_all_kernel<<<(xunits + wunits) / 256, 256, 0, stream>>>(
        x, Wq, Wk, Wv, Wp, xb, WtQKV, WtP, xunits);

    // QKV projection: Q (pre-scaled), K -> qkv2; V -> vT transposed
    gemm_dp_kernel<0, 96><<<768, 512, 0, stream>>>(xb, WtQKV, qkv2, vT, nullptr);

    // flash attention: 32 q-tiles x 64 bh, KV-parity split, LPT + XCD-grouped
    attn_kernel<<<B * 16 * 32, 256, 0, stream>>>(qkv2, vT, attn, T);

    // output projection (deep-pipeline): f32 + bias
    gemm_dp_kernel<1, 32><<<256, 512, 0, stream>>>(attn, WtP, out, nullptr, bp);
}

// Round 12
// 193.206 us; speedup vs baseline: 1.2568x; 1.2568x over previous
//
#include <hip/hip_runtime.h>
#include <stdint.h>
#include <math.h>

// ---------- types ----------
typedef short s16x8 __attribute__((ext_vector_type(8)));   // 8 bf16 (4 VGPR)
typedef float f32x4 __attribute__((ext_vector_type(4)));
typedef float f32x16 __attribute__((ext_vector_type(16)));

__device__ __forceinline__ unsigned short f2bf(float f) {
    union { float f; uint32_t u; } x; x.f = f;
    uint32_t r = x.u + 0x7FFFu + ((x.u >> 16) & 1u);   // RNE
    return (unsigned short)(r >> 16);
}

__device__ __forceinline__ uint32_t cvtpk_bf16(float lo, float hi) {
    uint32_t r;
    asm("v_cvt_pk_bf16_f32 %0, %1, %2" : "=v"(r) : "v"(lo), "v"(hi));
    return r;
}

#define GLD_LDS16(gp, lp) __builtin_amdgcn_global_load_lds( \
    (const __attribute__((address_space(1))) uint32_t*)(gp), \
    (__attribute__((address_space(3))) uint32_t*)(lp), 16, 0, 0)

#define MFMA16x16x32(a, b, c) __builtin_amdgcn_mfma_f32_16x16x32_bf16((a), (b), (c), 0, 0, 0)
#define MFMA32x32x16(a, b, c) __builtin_amdgcn_mfma_f32_32x32x16_bf16((a), (b), (c), 0, 0, 0)

// lane-half exchange
__device__ __forceinline__ void plswap(uint32_t a, uint32_t b, int lh, uint32_t& x, uint32_t& y) {
#if __has_builtin(__builtin_amdgcn_permlane32_swap)
    auto r = __builtin_amdgcn_permlane32_swap(a, b, false, false);
    x = (uint32_t)r[0]; y = (uint32_t)r[1];
#else
    uint32_t as = (uint32_t)__shfl_xor((int)a, 32, 64);
    uint32_t bs = (uint32_t)__shfl_xor((int)b, 32, 64);
    x = lh ? bs : a;
    y = lh ? b : as;
#endif
}

// ---------- merged convert kernel ----------
__global__ void cvt_all_kernel(const float* __restrict__ x,
                               const float* __restrict__ Wq, const float* __restrict__ Wk,
                               const float* __restrict__ Wv, const float* __restrict__ Wp,
                               unsigned short* __restrict__ xb,
                               unsigned short* __restrict__ WtQKV, unsigned short* __restrict__ WtP,
                               int xunits) {
    int u = blockIdx.x * blockDim.x + threadIdx.x;
    if (u < xunits) {
        int i = u * 4;
        float4 v = *(const float4*)(x + i);
        unsigned short o0 = f2bf(v.x), o1 = f2bf(v.y), o2 = f2bf(v.z), o3 = f2bf(v.w);
        uint64_t packed = (uint64_t)o0 | ((uint64_t)o1 << 16) | ((uint64_t)o2 << 32) | ((uint64_t)o3 << 48);
        *(uint64_t*)(xb + i) = packed;
        return;
    }
    int id = (u - xunits) * 4;               // 0 .. 4*1048576-1
    int which = id >> 20, rem = id & 1048575;
    const float* src = (which == 0) ? Wq : (which == 1) ? Wk : (which == 2) ? Wv : Wp;
    float4 v = *(const float4*)(src + rem);
    unsigned short* dst;
    if (which < 3) {
        int h = rem >> 16, c = (rem >> 6) & 1023, d = rem & 63;
        dst = WtQKV + (size_t)(which * 1024 + h * 64 + d) * 1024 + c;
    } else {
        int c = rem >> 10, n = rem & 1023;
        dst = WtP + (size_t)n * 1024 + c;
    }
    dst[0] = f2bf(v.x); dst[1024] = f2bf(v.y); dst[2048] = f2bf(v.z); dst[3072] = f2bf(v.w);
}

// ---------- unified deep-pipeline GEMM (T3+T4+T5), BM=128 BN=256 BK=32, 3-deep ----------
template<int MODE, int CPX>
__global__ __launch_bounds__(512, 4) void gemm_dp_kernel(
    const unsigned short* __restrict__ A, const unsigned short* __restrict__ Bt,
    void* __restrict__ Cout, unsigned short* __restrict__ vT,
    const float* __restrict__ bias)
{
    constexpr int K = 1024, NT = 32;     // K-tiles of 32
    __shared__ __align__(16) unsigned short LA[3][128 * 32];   // 8 KB each
    __shared__ __align__(16) unsigned short LB[3][256 * 32];   // 16 KB each

    const int t = threadIdx.x, w = t >> 6, l = t & 63, lr = l & 15, lg = l >> 4;
    const int wm2 = w >> 2, wn4 = w & 3;

    int bid = blockIdx.x;
    int swz = (bid & 7) * CPX + (bid >> 3);
    const int bm = (swz & 63) << 7, bn = (swz >> 6) << 8;

    const unsigned short* Ab = A + (size_t)bm * K;
    const unsigned short* Bb = Bt + (size_t)bn * K;

    int sArow, sAce, sBrow[2], sBce[2];
    {
        int u = t >> 4, x = (t & 15) ^ (u & 15);
        sArow = 4 * u + (x >> 2); sAce = (x & 3) << 3;
        #pragma unroll
        for (int i2 = 0; i2 < 2; ++i2) {
            int i = t + i2 * 512;
            int ub = i >> 4, xb2 = (i & 15) ^ (ub & 15);
            sBrow[i2] = 4 * ub + (xb2 >> 2); sBce[i2] = (xb2 & 3) << 3;
        }
    }

    int aoff[4], boff[4];
    #pragma unroll
    for (int m = 0; m < 4; ++m) {
        int u = 16 * wm2 + 4 * m + (lr >> 2);
        aoff[m] = u * 256 + (((lg + 4 * (lr & 3)) ^ (u & 15)) << 4);
    }
    #pragma unroll
    for (int n = 0; n < 4; ++n) {
        int u = 16 * wn4 + 4 * n + (lr >> 2);
        boff[n] = u * 256 + (((lg + 4 * (lr & 3)) ^ (u & 15)) << 4);
    }

    f32x4 acc[4][4] = {};

    GLD_LDS16(Ab + (size_t)sArow * K + 0 + sAce, &LA[0][t * 8]);
    #pragma unroll
    for (int i2 = 0; i2 < 2; ++i2)
        GLD_LDS16(Bb + (size_t)sBrow[i2] * K + 0 + sBce[i2], &LB[0][(t + i2 * 512) * 8]);
    GLD_LDS16(Ab + (size_t)sArow * K + 32 + sAce, &LA[1][t * 8]);
    #pragma unroll
    for (int i2 = 0; i2 < 2; ++i2)
        GLD_LDS16(Bb + (size_t)sBrow[i2] * K + 32 + sBce[i2], &LB[1][(t + i2 * 512) * 8]);
    asm volatile("s_waitcnt vmcnt(3)" ::: "memory");
    __builtin_amdgcn_sched_barrier(0);
    __builtin_amdgcn_s_barrier();

    int cur = 0;
    for (int j = 0; j < NT; ++j) {
        const int dst = (cur >= 1) ? cur - 1 : cur + 2;      // (j+2) % 3
        const bool st = (j + 2 < NT);
        const int k2 = (j + 2) << 5;
        s16x8 af[4], bfr[4];
        #pragma unroll
        for (int m = 0; m < 4; ++m)
            af[m] = *(const s16x8*)((const char*)LA[cur] + aoff[m]);
        #pragma unroll
        for (int n = 0; n < 4; ++n)
            bfr[n] = *(const s16x8*)((const char*)LB[cur] + boff[n]);
        if (st) {
            GLD_LDS16(Ab + (size_t)sArow * K + k2 + sAce, &LA[dst][t * 8]);
            #pragma unroll
            for (int i2 = 0; i2 < 2; ++i2)
                GLD_LDS16(Bb + (size_t)sBrow[i2] * K + k2 + sBce[i2], &LB[dst][(t + i2 * 512) * 8]);
        }
        __builtin_amdgcn_s_barrier();
        asm volatile("s_waitcnt lgkmcnt(0)" ::: "memory");
        __builtin_amdgcn_sched_barrier(0);
        __builtin_amdgcn_s_setprio(1);
        #pragma unroll
        for (int m = 0; m < 4; ++m)
            #pragma unroll
            for (int n = 0; n < 4; ++n)
                acc[m][n] = MFMA16x16x32(af[m], bfr[n], acc[m][n]);
        __builtin_amdgcn_s_setprio(0);
        if (j + 1 < NT) {
            if (st) { asm volatile("s_waitcnt vmcnt(3)" ::: "memory"); }
            else    { asm volatile("s_waitcnt vmcnt(0)" ::: "memory"); }
            __builtin_amdgcn_sched_barrier(0);
        }
        __builtin_amdgcn_s_barrier();
        cur = (cur == 2) ? 0 : cur + 1;
    }

    if (MODE == 1) {
        float* C = (float*)Cout;
        #pragma unroll
        for (int mi = 0; mi < 4; ++mi)
            #pragma unroll
            for (int ni = 0; ni < 4; ++ni) {
                int col = bn + wn4 * 64 + ni * 16 + lr;
                float bv = bias[col];
                int row0 = bm + wm2 * 64 + mi * 16 + lg * 4;
                #pragma unroll
                for (int r = 0; r < 4; ++r)
                    C[(size_t)(row0 + r) * 1024 + col] = acc[mi][ni][r] + bv;
            }
    } else {
        unsigned short* qkv2 = (unsigned short*)Cout;
        const bool isV = (bn >= 2048);
        const float sc = (bn < 1024) ? (0.03125f * 1.44269504088896341f) : 1.0f;
        #pragma unroll
        for (int mi = 0; mi < 4; ++mi)
            #pragma unroll
            for (int ni = 0; ni < 4; ++ni) {
                int col = bn + wn4 * 64 + ni * 16 + lr;
                int row0 = bm + wm2 * 64 + mi * 16 + lg * 4;
                if (!isV) {
                    #pragma unroll
                    for (int r = 0; r < 4; ++r)
                        qkv2[(size_t)(row0 + r) * 2048 + col] = f2bf(acc[mi][ni][r] * sc);
                } else {
                    int h = (col >> 6) & 15, d = col & 63;
                    size_t vb = ((size_t)((row0 >> 11) * 16 + h) * 64 + d) * 2048 + (row0 & 2047);
                    uint32_t u0 = (uint32_t)f2bf(acc[mi][ni][0]) | ((uint32_t)f2bf(acc[mi][ni][1]) << 16);
                    uint32_t u1 = (uint32_t)f2bf(acc[mi][ni][2]) | ((uint32_t)f2bf(acc[mi][ni][3]) << 16);
                    *(uint32_t*)&vT[vb]     = u0;
                    *(uint32_t*)&vT[vb + 2] = u1;
                }
            }
    }
}

// ---------- flash attention: KV-parity split, 32x32 MFMA, in-register P ----------
// Wave (ws, wp): slice ws owns 32 q-rows; parity wp processes s in [32wp, 32wp+32)
// of each 64-kv LDS tile. Private (m,l,o) per wave; LDS combine at block end.
// S^T = mfma(K, Q): col q = lane&31, s_loc = (r&3)+8*(r>>2)+4*lh (within half).
// LDS tiles 64 rows x 128 B: super-row u = row>>1 (256 B, 16 slots of 16 B);
// slot = (chunk + 8*(row&1)) ^ (u & 15).
// NOTE (R11 lesson): do NOT add an f32x16 l_acc here — it spills (FETCH/WRITE
// +110 MB, attn 83->142 us). VALU row-sum is cheaper than spilled registers.
__device__ __forceinline__ void proc32h(
    const unsigned short* __restrict__ Ksb, const unsigned short* __restrict__ Vtb,
    const s16x8* qf, f32x16* o, float& m_r, float& l_r,
    int qms, bool domask, int lq, int lh, int wp)
{
    const int ub = lq >> 1;
    const int vb8 = (lq & 1) << 3;
    f32x16 S = {};
    __builtin_amdgcn_s_setprio(1);
    #pragma unroll
    for (int kd = 0; kd < 4; ++kd) {
        s16x8 kf = *(const s16x8*)((const char*)Ksb + (wp * 16 + ub) * 256
                                   + ((((2 * kd + lh) + vb8) ^ ub) << 4));
        S = MFMA32x32x16(kf, qf[kd], S);
    }
    __builtin_amdgcn_s_setprio(0);
    if (domask) {
        #pragma unroll
        for (int r = 0; r < 16; ++r) {
            int s_loc = (r & 3) + 8 * (r >> 2) + 4 * lh;
            S[r] = (s_loc <= qms) ? S[r] : -1e30f;
        }
    }
    // row max over this half: tree over 16 regs + 1 shuffle (lane^32 = other s_loc set)
    float zm = fmaxf(S[0], S[1]);
    #pragma unroll
    for (int r = 2; r < 16; r += 2) zm = fmaxf(fmaxf(zm, S[r]), S[r + 1]);
    zm = fmaxf(zm, __shfl_xor(zm, 32, 64));
    const bool defer = (__all(zm <= m_r + 8.0f) != 0);   // T13
    if (!defer) {
        float mn = fmaxf(m_r, zm);
        float alpha = exp2f(m_r - mn);
        m_r = mn;
        l_r *= alpha;
        o[0] *= alpha;
        o[1] *= alpha;
    }
    float rs = 0.0f;
    uint32_t pk[8];
    #pragma unroll
    for (int r = 0; r < 16; ++r) {
        float pv = exp2f(S[r] - m_r);
        S[r] = pv;
        rs += pv;
    }
    #pragma unroll
    for (int hh = 0; hh < 8; ++hh)
        pk[hh] = cvtpk_bf16(S[2 * hh], S[2 * hh + 1]);
    rs += __shfl_xor(rs, 32, 64);
    l_r += rs;
    // pf[jj]: B-frag P^T for k = s = 32*wp + 16*jj + 8*lh + j
    s16x8 pf[2];
    #pragma unroll
    for (int jj = 0; jj < 2; ++jj) {
        uint32_t w0, w1, w2, w3;
        plswap(pk[4 * jj + 0], pk[4 * jj + 2], lh, w0, w2);
        plswap(pk[4 * jj + 1], pk[4 * jj + 3], lh, w1, w3);
        union { uint32_t u[4]; s16x8 v; } pu;
        pu.u[0] = w0; pu.u[1] = w1; pu.u[2] = w2; pu.u[3] = w3;
        pf[jj] = pu.v;
    }
    __builtin_amdgcn_s_setprio(1);
    #pragma unroll
    for (int dblk = 0; dblk < 2; ++dblk)
        #pragma unroll
        for (int jj = 0; jj < 2; ++jj) {
            int kc = 2 * (2 * wp + jj) + lh;
            s16x8 vf = *(const s16x8*)((const char*)Vtb + (dblk * 16 + ub) * 256
                                       + (((kc + vb8) ^ ub) << 4));
            o[dblk] = MFMA32x32x16(vf, pf[jj], o[dblk]);
        }
    __builtin_amdgcn_s_setprio(0);
}

// Block = 256 threads = 4 waves; one 64-row q-tile; waves: slice (w&1) x parity (w>>1).
// blockIdx decode: g = i&7 (XCD group = bh%8), j = i>>3; tq = 31-(j>>3) (LPT),
// bh = ((j&7)<<3)|g.
__global__ __launch_bounds__(256, 5) void attn_kernel(
    const unsigned short* __restrict__ qkv2, const unsigned short* __restrict__ vT,
    unsigned short* __restrict__ attnO, int T)
{
    __shared__ __align__(16) unsigned short SMEM[4][64 * 64];   // K0,K1,V0,V1; combine reuse

    const int i = blockIdx.x;
    const int g = i & 7, j = i >> 3;
    const int tq = 31 - (j >> 3);
    const int bh = ((j & 7) << 3) | g;
    const int b = bh >> 4, h = bh & 15;
    const int nkv = tq + 1;

    const int t = threadIdx.x, w = t >> 6, l = t & 63, lq = l & 31, lh = l >> 5;
    const int ws = w & 1, wp = w >> 1;
    const int c0 = tq * 64 + 32 * ws;

    const unsigned short* qbase = qkv2 + (size_t)b * T * 2048;
    const unsigned short* kbase = qbase + 1024 + h * 64;
    const unsigned short* vtb   = vT + (size_t)(b * 16 + h) * 64 * 2048;

    s16x8 qf[4];
    #pragma unroll
    for (int kd = 0; kd < 4; ++kd)
        qf[kd] = *(const s16x8*)(qbase + (size_t)(c0 + lq) * 2048 + h * 64 + kd * 16 + lh * 8);

    f32x16 o[2] = {};
    float m_r = -1e30f, l_r = 0.0f;

    // staging: 256 threads x 2 chunks per tile (512 chunks of 16 B each)
    int srow[2], sch[2];
    #pragma unroll
    for (int i2 = 0; i2 < 2; ++i2) {
        int c = t + i2 * 256;
        int su = c >> 4, sx = (c & 15) ^ (su & 15);
        srow[i2] = 2 * su + (sx >> 3); sch[i2] = (sx & 7) << 3;
    }
    auto STAGE = [&](int buf, int s0) {
        #pragma unroll
        for (int i2 = 0; i2 < 2; ++i2) {
            int c = t + i2 * 256;
            GLD_LDS16(kbase + (size_t)(s0 + srow[i2]) * 2048 + sch[i2], &SMEM[buf][c * 8]);
            GLD_LDS16(vtb + (size_t)srow[i2] * 2048 + s0 + sch[i2], &SMEM[2 + buf][c * 8]);
        }
    };

    STAGE(0, 0);
    __syncthreads();

    for (int kt = 0; kt < nkv; ++kt) {
        const int cur = kt & 1, nxt = cur ^ 1;
        if (kt + 1 < nkv) STAGE(nxt, (kt + 1) * 64);
        const int sbase = 64 * kt + 32 * wp;
        if (sbase <= c0 + 31)                                   // wave-uniform
            proc32h(SMEM[cur], SMEM[2 + cur], qf, o, m_r, l_r,
                    c0 + lq - sbase, sbase + 31 > c0, lq, lh, wp);
        __syncthreads();
    }

    // ---- combine the two kv-parity halves (pairs w and w^2) through LDS ----
    float* fs = (float*)&SMEM[0][0];
    if (lh == 0) { fs[w * 64 + lq * 2] = m_r; fs[w * 64 + lq * 2 + 1] = l_r; }
    __syncthreads();
    float m_o = fs[(w ^ 2) * 64 + lq * 2], l_o = fs[(w ^ 2) * 64 + lq * 2 + 1];
    float M = fmaxf(m_r, m_o);
    float s_self = exp2f(m_r - M);
    float s_oth  = exp2f(m_o - M);
    float L = l_r * s_self + l_o * s_oth;
    float fsc = s_self / L;
    __syncthreads();                                            // ml region reused below
    float* cb = fs + ws * 2048;                                 // 8 KB per slice pair
    if (wp == 1) {
        #pragma unroll
        for (int dblk = 0; dblk < 2; ++dblk)
            #pragma unroll
            for (int r = 0; r < 16; ++r)
                cb[(dblk * 16 + r) * 64 + lq * 2 + lh] = o[dblk][r] * fsc;
    }
    __syncthreads();
    if (wp == 0) {
        #pragma unroll
        for (int dblk = 0; dblk < 2; ++dblk)
            #pragma unroll
            for (int r = 0; r < 16; r += 2) {
                float v0 = o[dblk][r] * fsc     + cb[(dblk * 16 + r) * 64 + lq * 2 + lh];
                float v1 = o[dblk][r + 1] * fsc + cb[(dblk * 16 + r + 1) * 64 + lq * 2 + lh];
                int d = dblk * 32 + (r & 3) + 8 * (r >> 2) + 4 * lh;
                uint32_t ua = cvtpk_bf16(v0, v1);
                *(uint32_t*)&attnO[(size_t)(b * T + c0 + lq) * 1024 + h * 64 + d] = ua;
            }
    }
}

// ---------- launch ----------
extern "C" void kernel_launch(void* const* d_in, const int* in_sizes, int n_in,
                              void* d_out, int out_size, void* d_ws, size_t ws_size,
                              hipStream_t stream) {
    const float* x  = (const float*)d_in[0];
    const float* Wq = (const float*)d_in[1];
    const float* Wk = (const float*)d_in[2];
    const float* Wv = (const float*)d_in[3];
    const float* Wp = (const float*)d_in[4];
    const float* bp = (const float*)d_in[5];
    float* out = (float*)d_out;

    const int T = 2048, C = 1024;
    const int BT = in_sizes[0] / C;      // 8192
    const int B  = BT / T;               // 4

    // workspace layout (bytes), total 92,274,688
    char* ws = (char*)d_ws;
    unsigned short* xb    = (unsigned short*)(ws);                        // 16,777,216
    unsigned short* WtQKV = (unsigned short*)(ws + 16777216);             //  6,291,456
    unsigned short* WtP   = (unsigned short*)(ws + 23068672);             //  2,097,152
    unsigned short* qkv2  = (unsigned short*)(ws + 25165824);             // 33,554,432 [8192][2048]
    unsigned short* vT    = (unsigned short*)(ws + 58720256);             // 16,777,216 [(b,h,d)][2048]
    unsigned short* attn  = (unsigned short*)(ws + 75497472);             // 16,777,216
    (void)ws_size; (void)n_in; (void)out_size;

    const int xunits = BT * C / 4;                       // 2,097,152
    const int wunits = 4 * 1024 * 1024 / 4;              // 1,048,576
    cvt_all_kernel<<<(xunits + wunits) / 256, 256, 0, stream>>>(
        x, Wq, Wk, Wv, Wp, xb, WtQKV, WtP, xunits);

    // QKV projection: Q (pre-scaled), K -> qkv2; V -> vT transposed
    gemm_dp_kernel<0, 96><<<768, 512, 0, stream>>>(xb, WtQKV, qkv2, vT, nullptr);

    // flash attention: 32 q-tiles x 64 bh, KV-parity split, LPT + XCD-grouped
    attn_kernel<<<B * 16 * 32, 256, 0, stream>>>(qkv2, vT, attn, T);

    // output projection (deep-pipeline): f32 + bias
    gemm_dp_kernel<1, 32><<<256, 512, 0, stream>>>(attn, WtP, out, nullptr, bp);
}